// Round 5
// baseline (279.937 us; speedup 1.0000x reference)
//
#include <hip/hip_runtime.h>
#include <hip/hip_bf16.h>

typedef __attribute__((ext_vector_type(8))) short short8;
typedef __attribute__((ext_vector_type(4))) float f32x4;

#define N_PROP 512
#define DHID   1024
#define KFLAT  50176
#define SM_SCALE 0.03125f  /* 1/sqrt(1024) */

__device__ inline short f2bf(float x) {
  __hip_bfloat16 b = __float2bfloat16(x);
  return __builtin_bit_cast(short, b);
}
__device__ inline float bf2f(unsigned short u) {
  unsigned int x = (unsigned int)u << 16;
  return __builtin_bit_cast(float, x);
}

__device__ inline void gl16(const float* g, float* l) {
  __builtin_amdgcn_global_load_lds(
      (const __attribute__((address_space(1))) void*)g,
      (__attribute__((address_space(3))) void*)l, 16, 0, 0);
}

// ---------------- fc1: dedicated global_load_lds double-buffered kernel ----
// C-partials[y] = A(128-tile) @ B(128-tile)^T over klen=1600 (tail 576), BK=32.
// fp32 LDS, DMA-staged (linear dest); XOR swizzle (chunk ^ row&7) applied to the
// GLOBAL source and the LDS read (rule: both-sides-or-neither). One barrier per
// K-step; next tile's 8 gload_lds stay in flight across compute (T3-minimal).
__global__ __launch_bounds__(256, 2)
void gemm_fc1(const float* __restrict__ A, const float* __restrict__ B,
              __hip_bfloat16* __restrict__ parts)
{
  __shared__ float sA[2][128 * 32];
  __shared__ float sB[2][128 * 32];   // total 64 KB (2 blocks/CU)

  // bijective XCD swizzle, slice-major: XCD j gets 4 consecutive K-slices.
  const int n = gridDim.x;
  int lid = blockIdx.x;
  lid = (lid & 7) * (n >> 3) + (lid >> 3);
  const int y    = lid >> 5;           // 32 tiles per slice
  const int tile = lid & 31;
  const int tm = tile >> 3;            // 4 M-tiles
  const int tn = tile & 7;             // 8 N-tiles

  const int k0 = y * 1600;
  const int krem = KFLAT - k0;
  const int klen_eff = krem < 1600 ? krem : 1600;
  const int nt = klen_eff >> 5;        // 25 (tail slice: 18)

  const int tid  = threadIdx.x;
  const int lane = tid & 63;
  const int wid  = tid >> 6;
  const int wm = wid >> 1, wn = wid & 1;
  const int l16 = lane & 15, kq = lane >> 4;

  const float* Ab = A + (size_t)(tm * 128) * KFLAT;
  const float* Bb = B + (size_t)(tn * 128) * KFLAT;

  // staging geometry: wave w stages rows [w*32, w*32+32) of both tiles,
  // 4 ops each of 64 lanes x 16B = 8 rows (row = 32 fp32 = 128 B).
  const int srow   = wid * 32 + (lane >> 3);     // + i*8
  const int schunk = (lane & 7) ^ (lane >> 3);   // pre-swizzled global 16B-chunk

  f32x4 acc[4][4];
  #pragma unroll
  for (int i = 0; i < 4; ++i)
    #pragma unroll
    for (int j = 0; j < 4; ++j)
      acc[i][j] = (f32x4){0.f, 0.f, 0.f, 0.f};

  auto stage = [&](int b, int kk) {
    #pragma unroll
    for (int i = 0; i < 4; ++i) {
      const float* ga = Ab + (size_t)(srow + i * 8) * KFLAT + kk + schunk * 4;
      const float* gb = Bb + (size_t)(srow + i * 8) * KFLAT + kk + schunk * 4;
      gl16(ga, &sA[b][(wid * 32 + i * 8) * 32]);
      gl16(gb, &sB[b][(wid * 32 + i * 8) * 32]);
    }
  };

  auto compute = [&](int b) {
    short8 af[4], bf[4];
    #pragma unroll
    for (int i = 0; i < 4; ++i) {
      int R = wm * 64 + i * 16 + l16;
      int m = l16 & 7;
      int s0 = (2 * kq) ^ m, s1 = (2 * kq + 1) ^ m;
      float4 a0 = *(const float4*)&sA[b][R * 32 + s0 * 4];
      float4 a1 = *(const float4*)&sA[b][R * 32 + s1 * 4];
      short8 s;
      s[0]=f2bf(a0.x); s[1]=f2bf(a0.y); s[2]=f2bf(a0.z); s[3]=f2bf(a0.w);
      s[4]=f2bf(a1.x); s[5]=f2bf(a1.y); s[6]=f2bf(a1.z); s[7]=f2bf(a1.w);
      af[i] = s;
    }
    #pragma unroll
    for (int j = 0; j < 4; ++j) {
      int R = wn * 64 + j * 16 + l16;
      int m = l16 & 7;
      int s0 = (2 * kq) ^ m, s1 = (2 * kq + 1) ^ m;
      float4 b0 = *(const float4*)&sB[b][R * 32 + s0 * 4];
      float4 b1 = *(const float4*)&sB[b][R * 32 + s1 * 4];
      short8 s;
      s[0]=f2bf(b0.x); s[1]=f2bf(b0.y); s[2]=f2bf(b0.z); s[3]=f2bf(b0.w);
      s[4]=f2bf(b1.x); s[5]=f2bf(b1.y); s[6]=f2bf(b1.z); s[7]=f2bf(b1.w);
      bf[j] = s;
    }
    #pragma unroll
    for (int i = 0; i < 4; ++i)
      #pragma unroll
      for (int j = 0; j < 4; ++j)
        acc[i][j] = __builtin_amdgcn_mfma_f32_16x16x32_bf16(af[i], bf[j], acc[i][j], 0, 0, 0);
  };

  stage(0, k0);
  asm volatile("s_waitcnt vmcnt(0)" ::: "memory");
  __syncthreads();

  int cur = 0;
  for (int t = 0; t < nt; ++t) {
    if (t + 1 < nt) stage(cur ^ 1, k0 + (t + 1) * 32);
    compute(cur);
    asm volatile("s_waitcnt vmcnt(0)" ::: "memory");
    __syncthreads();
    cur ^= 1;
  }

  __hip_bfloat16* P = parts + (size_t)y * (N_PROP * DHID);
  const int crow0 = tm * 128 + wm * 64;
  const int ccol0 = tn * 128 + wn * 64;
  #pragma unroll
  for (int i = 0; i < 4; ++i)
    #pragma unroll
    for (int j = 0; j < 4; ++j)
      #pragma unroll
      for (int e = 0; e < 4; ++e) {
        int r = crow0 + i * 16 + kq * 4 + e;
        int c = ccol0 + j * 16 + l16;
        P[(size_t)r * DHID + c] = __float2bfloat16(acc[i][j][e]);
      }
}

// ---------------- generic NT GEMM (small ops) — unchanged from round 4 ------
template<int BM, int BN, int BK, int MINW>
__global__ __launch_bounds__(256, MINW)
void gemm_nt(const float* __restrict__ A, int lda,
             const float* __restrict__ B1, const float* __restrict__ B2, int ldb,
             float* __restrict__ C, __hip_bfloat16* __restrict__ Cb, int ldc,
             int tiles_per_slice, int tiles_n,
             int klen, int ktot,
             size_t c_split_stride, size_t c_z_stride,
             const float* __restrict__ bias1, const float* __restrict__ bias2,
             const float* __restrict__ res1, const float* __restrict__ res2,
             float* __restrict__ Ct, int ldct,
             int do_relu)
{
  constexpr int BKP = BK + 8;
  constexpr int WM = BM / 2, WN = BN / 2;
  constexpr int FM = WM / 16, FN = WN / 16;
  constexpr int NCH = BK / 8;
  constexpr int CHA = (BM * BK) / (8 * 256);
  constexpr int CHB = (BN * BK) / (8 * 256);

  __shared__ short As[BM * BKP];
  __shared__ short Bs[BN * BKP];

  const int n = gridDim.x;
  int lid = blockIdx.x;
  lid = (lid & 7) * (n >> 3) + (lid >> 3);

  const int y    = lid / tiles_per_slice;
  const int tile = lid % tiles_per_slice;
  const int tm = tile / tiles_n;
  const int tn = tile % tiles_n;

  const int k0 = y * klen;
  const int krem = ktot - k0;
  const int klen_eff = krem < klen ? krem : klen;
  const int nt = klen_eff / BK;

  const size_t coff = (size_t)y * c_split_stride + (size_t)blockIdx.z * c_z_stride;
  if (C)  C  += coff;
  if (Cb) Cb += coff;
  const float* B    = blockIdx.z ? B2 : B1;
  const float* bias = blockIdx.z ? bias2 : bias1;

  const int tid  = threadIdx.x;
  const int lane = tid & 63;
  const int wid  = tid >> 6;
  const int wm = wid >> 1, wn = wid & 1;
  const int l16 = lane & 15, kq = lane >> 4;

  const float* Abase = A + (size_t)(tm * BM) * lda;
  const float* Bbase = B + (size_t)(tn * BN) * ldb;

  f32x4 acc[FM][FN];
  #pragma unroll
  for (int i = 0; i < FM; ++i)
    #pragma unroll
    for (int j = 0; j < FN; ++j)
      acc[i][j] = (f32x4){0.f, 0.f, 0.f, 0.f};

  float4 ra[CHA][2], rb[CHB][2];

  auto loadA = [&](int kk) {
    #pragma unroll
    for (int i = 0; i < CHA; ++i) {
      int ch = tid + i * 256;
      int r = ch / NCH, cc = ch % NCH;
      const float* p = Abase + (size_t)r * lda + kk + cc * 8;
      ra[i][0] = *(const float4*)p;
      ra[i][1] = *(const float4*)(p + 4);
    }
  };
  auto loadB = [&](int kk) {
    #pragma unroll
    for (int i = 0; i < CHB; ++i) {
      int ch = tid + i * 256;
      int r = ch / NCH, cc = ch % NCH;
      const float* p = Bbase + (size_t)r * ldb + kk + cc * 8;
      rb[i][0] = *(const float4*)p;
      rb[i][1] = *(const float4*)(p + 4);
    }
  };
  auto storeAB = [&]() {
    #pragma unroll
    for (int i = 0; i < CHA; ++i) {
      int ch = tid + i * 256;
      int r = ch / NCH, cc = ch % NCH;
      float4 u = ra[i][0], v = ra[i][1];
      short8 s;
      s[0]=f2bf(u.x); s[1]=f2bf(u.y); s[2]=f2bf(u.z); s[3]=f2bf(u.w);
      s[4]=f2bf(v.x); s[5]=f2bf(v.y); s[6]=f2bf(v.z); s[7]=f2bf(v.w);
      *(short8*)&As[r * BKP + cc * 8] = s;
    }
    #pragma unroll
    for (int i = 0; i < CHB; ++i) {
      int ch = tid + i * 256;
      int r = ch / NCH, cc = ch % NCH;
      float4 u = rb[i][0], v = rb[i][1];
      short8 s;
      s[0]=f2bf(u.x); s[1]=f2bf(u.y); s[2]=f2bf(u.z); s[3]=f2bf(u.w);
      s[4]=f2bf(v.x); s[5]=f2bf(v.y); s[6]=f2bf(v.z); s[7]=f2bf(v.w);
      *(short8*)&Bs[r * BKP + cc * 8] = s;
    }
  };

  loadA(k0); loadB(k0);
  storeAB();
  __syncthreads();

  for (int t = 0; t < nt; ++t) {
    if (t + 1 < nt) { loadA(k0 + (t + 1) * BK); loadB(k0 + (t + 1) * BK); }

    #pragma unroll
    for (int ks = 0; ks < BK / 32; ++ks) {
      short8 af[FM], bf[FN];
      #pragma unroll
      for (int i = 0; i < FM; ++i)
        af[i] = *(short8*)&As[(wm * WM + i * 16 + l16) * BKP + ks * 32 + kq * 8];
      #pragma unroll
      for (int j = 0; j < FN; ++j)
        bf[j] = *(short8*)&Bs[(wn * WN + j * 16 + l16) * BKP + ks * 32 + kq * 8];
      #pragma unroll
      for (int i = 0; i < FM; ++i)
        #pragma unroll
        for (int j = 0; j < FN; ++j)
          acc[i][j] = __builtin_amdgcn_mfma_f32_16x16x32_bf16(af[i], bf[j], acc[i][j], 0, 0, 0);
    }

    __syncthreads();
    if (t + 1 < nt) storeAB();
    __syncthreads();
  }

  const int crow0 = tm * BM + wm * WM;
  const int ccol0 = tn * BN + wn * WN;
  #pragma unroll
  for (int i = 0; i < FM; ++i)
    #pragma unroll
    for (int j = 0; j < FN; ++j)
      #pragma unroll
      for (int e = 0; e < 4; ++e) {
        int r = crow0 + i * 16 + kq * 4 + e;
        int c = ccol0 + j * 16 + l16;
        float v = acc[i][j][e];
        if (bias) v += bias[c];
        if (res1) v += res1[(size_t)r * ldc + c];
        if (res2) v += res2[(size_t)r * ldc + c];
        if (do_relu) v = fmaxf(v, 0.f);
        if (Cb) Cb[(size_t)r * ldc + c] = __float2bfloat16(v);
        else    C [(size_t)r * ldc + c] = v;
        if (Ct) Ct[(size_t)c * ldct + r] = v;
      }
}

__global__ __launch_bounds__(256)
void reduce_bias(const __hip_bfloat16* __restrict__ parts, int sk, size_t stride,
                 const float* __restrict__ bias, float* __restrict__ out)
{
  int idx4 = blockIdx.x * 256 + threadIdx.x;
  int c4 = idx4 & (DHID / 4 - 1);
  float4 b = *(const float4*)(bias + (size_t)c4 * 4);
  float s0 = b.x, s1 = b.y, s2 = b.z, s3 = b.w;
  for (int i = 0; i < sk; ++i) {
    const __hip_bfloat16* p = parts + (size_t)i * stride + (size_t)idx4 * 4;
    ushort4 u = *(const ushort4*)p;
    s0 += bf2f(u.x); s1 += bf2f(u.y); s2 += bf2f(u.z); s3 += bf2f(u.w);
  }
  float4 o = {s0, s1, s2, s3};
  *(float4*)(out + (size_t)idx4 * 4) = o;
}

__global__ __launch_bounds__(256)
void transpose_k(const float* __restrict__ in, float* __restrict__ out, int R, int Cc)
{
  __shared__ float t[32][33];
  int bx = blockIdx.x * 32;
  int by = blockIdx.y * 32;
  int tx = threadIdx.x & 31, ty = threadIdx.x >> 5;
  #pragma unroll
  for (int i = 0; i < 4; ++i)
    t[ty + i * 8][tx] = in[(size_t)(by + ty + i * 8) * Cc + bx + tx];
  __syncthreads();
  #pragma unroll
  for (int i = 0; i < 4; ++i)
    out[(size_t)(bx + ty + i * 8) * R + by + tx] = t[tx][ty + i * 8];
}

__global__ __launch_bounds__(256)
void softmax_rows(float* __restrict__ x, float scale)
{
  int row = blockIdx.x;
  float* p = x + (size_t)row * N_PROP;
  int tid = threadIdx.x;
  float a = p[tid] * scale;
  float b = p[tid + 256] * scale;
  float m = fmaxf(a, b);
  #pragma unroll
  for (int o = 32; o > 0; o >>= 1) m = fmaxf(m, __shfl_xor(m, o));
  __shared__ float sm[4], ss[4];
  int w = tid >> 6;
  if ((tid & 63) == 0) sm[w] = m;
  __syncthreads();
  m = fmaxf(fmaxf(sm[0], sm[1]), fmaxf(sm[2], sm[3]));
  float ea = __expf(a - m), eb = __expf(b - m);
  float s = ea + eb;
  #pragma unroll
  for (int o = 32; o > 0; o >>= 1) s += __shfl_xor(s, o);
  if ((tid & 63) == 0) ss[w] = s;
  __syncthreads();
  s = ss[0] + ss[1] + ss[2] + ss[3];
  float inv = 1.f / s;
  p[tid] = ea * inv;
  p[tid + 256] = eb * inv;
}

extern "C" void kernel_launch(void* const* d_in, const int* in_sizes, int n_in,
                              void* d_out, int out_size, void* d_ws, size_t ws_size,
                              hipStream_t stream)
{
  (void)in_sizes; (void)n_in; (void)out_size; (void)ws_size;
  const float* x      = (const float*)d_in[0];
  const float* fc1_w  = (const float*)d_in[1];
  const float* fc1_b  = (const float*)d_in[2];
  const float* fc2_w  = (const float*)d_in[3];
  const float* fc2_b  = (const float*)d_in[4];
  const float* a1w1   = (const float*)d_in[5];
  const float* a1b1   = (const float*)d_in[6];
  const float* a1w2   = (const float*)d_in[7];
  const float* a1b2   = (const float*)d_in[8];
  const float* a1cw   = (const float*)d_in[9];
  const float* a1cb   = (const float*)d_in[10];
  const float* a2w1   = (const float*)d_in[11];
  const float* a2b1   = (const float*)d_in[12];
  const float* a2w2   = (const float*)d_in[13];
  const float* a2b2   = (const float*)d_in[14];
  const float* a2cw   = (const float*)d_in[15];
  const float* a2cb   = (const float*)d_in[16];
  float* out = (float*)d_out;

  char* ws = (char*)d_ws;
  const size_t SZ = (size_t)N_PROP * DHID * 4;      // 2 MB
  float* out0   = (float*)(ws + 0 * SZ);
  float* h0     = (float*)(ws + 1 * SZ);
  float* h1     = (float*)(ws + 2 * SZ);
  float* T      = (float*)(ws + 3 * SZ);
  float* q      = (float*)(ws + 4 * SZ);
  float* k      = (float*)(ws + 5 * SZ);            // adjacent to q (dual-z)
  float* att    = (float*)(ws + 6 * SZ);
  float* logits = (float*)(ws + 7 * SZ);
  __hip_bfloat16* parts =
      (__hip_bfloat16*)(ws + 7 * SZ + (size_t)N_PROP * N_PROP * 4);  // 32 x 1 MB

  const size_t ND = (size_t)N_PROP * DHID;
  const int SK = 32;
  dim3 blk(256);

  // ---- fc1 ----
  gemm_fc1<<<dim3(32 * SK), blk, 0, stream>>>(x, fc1_w, parts);
  reduce_bias<<<(N_PROP * DHID) / 1024, blk, 0, stream>>>(parts, SK, ND, fc1_b, out0);

  // ---- attention 1 on out0 ----
  transpose_k<<<dim3(DHID / 32, N_PROP / 32), blk, 0, stream>>>(out0, T, N_PROP, DHID);
  gemm_nt<32, 64, 128, 2><<<dim3(256, 1, 2), blk, 0, stream>>>(
      out0, DHID, a1w1, a1w2, DHID,
      q, nullptr, DHID,
      256, 16, DHID, DHID,
      0, ND,
      a1b1, a1b2, nullptr, nullptr, nullptr, 0, 0);
  gemm_nt<32, 32, 128, 2><<<dim3(256), blk, 0, stream>>>(
      q, DHID, k, nullptr, DHID,
      logits, nullptr, N_PROP,
      256, 16, DHID, DHID,
      0, 0,
      nullptr, nullptr, nullptr, nullptr, nullptr, 0, 0);
  softmax_rows<<<N_PROP, blk, 0, stream>>>(logits, SM_SCALE);
  gemm_nt<32, 64, 128, 2><<<dim3(256), blk, 0, stream>>>(
      logits, N_PROP, T, nullptr, N_PROP,
      att, nullptr, DHID,
      256, 16, N_PROP, N_PROP,
      0, 0,
      nullptr, nullptr, nullptr, nullptr, nullptr, 0, 0);
  gemm_nt<32, 64, 128, 2><<<dim3(256), blk, 0, stream>>>(
      att, DHID, a1cw, nullptr, DHID,
      h0, nullptr, DHID,
      256, 16, DHID, DHID,
      0, 0,
      a1cb, nullptr, out0, nullptr, nullptr, 0, 1);
  gemm_nt<32, 64, 128, 2><<<dim3(256), blk, 0, stream>>>(
      h0, DHID, fc2_w, nullptr, DHID,
      h1, nullptr, DHID,
      256, 16, DHID, DHID,
      0, 0,
      fc2_b, nullptr, nullptr, nullptr, T, N_PROP, 0);

  // ---- attention 2 on h1 ----
  gemm_nt<32, 64, 128, 2><<<dim3(256, 1, 2), blk, 0, stream>>>(
      h1, DHID, a2w1, a2w2, DHID,
      q, nullptr, DHID,
      256, 16, DHID, DHID,
      0, ND,
      a2b1, a2b2, nullptr, nullptr, nullptr, 0, 0);
  gemm_nt<32, 32, 128, 2><<<dim3(256), blk, 0, stream>>>(
      q, DHID, k, nullptr, DHID,
      logits, nullptr, N_PROP,
      256, 16, DHID, DHID,
      0, 0,
      nullptr, nullptr, nullptr, nullptr, nullptr, 0, 0);
  softmax_rows<<<N_PROP, blk, 0, stream>>>(logits, SM_SCALE);
  gemm_nt<32, 64, 128, 2><<<dim3(256), blk, 0, stream>>>(
      logits, N_PROP, T, nullptr, N_PROP,
      att, nullptr, DHID,
      256, 16, N_PROP, N_PROP,
      0, 0,
      nullptr, nullptr, nullptr, nullptr, nullptr, 0, 0);
  gemm_nt<32, 64, 128, 2><<<dim3(256), blk, 0, stream>>>(
      att, DHID, a2cw, nullptr, DHID,
      out, nullptr, DHID,
      256, 16, DHID, DHID,
      0, 0,
      a2cb, nullptr, h1, out0, nullptr, 0, 1);
}

// Round 6
// 256.485 us; speedup vs baseline: 1.0914x; 1.0914x over previous
//
#include <hip/hip_runtime.h>
#include <hip/hip_bf16.h>

typedef __attribute__((ext_vector_type(8))) short short8;
typedef __attribute__((ext_vector_type(4))) float f32x4;

#define N_PROP 512
#define DHID   1024
#define KFLAT  50176
#define SM_SCALE 0.03125f  /* 1/sqrt(1024) */

__device__ inline short f2bf(float x) {
  __hip_bfloat16 b = __float2bfloat16(x);
  return __builtin_bit_cast(short, b);
}
__device__ inline float bf2f(unsigned short u) {
  unsigned int x = (unsigned int)u << 16;
  return __builtin_bit_cast(float, x);
}

// ---------------- fc1: bf16-LDS double-buffered, 1 barrier per K-step --------
// parts[y] = A(128-tile) @ B(128-tile)^T over klen=1600 (tail 576), BK=64.
// Staging: global fp32 -> regs -> convert once -> bf16 LDS (ds_write overlaps
// other waves' MFMA on the other buffer). 2-deep load pipeline (t+2 issued at t).
// LDS 73.7 KB -> 2 blocks/CU. VGPR ~170 (acc 64 + stage 64) — do NOT raise MINW
// (round-3 lesson: capping VGPRs below the live set spills to scratch).
__global__ __launch_bounds__(256, 2)
void gemm_fc1(const float* __restrict__ A, const float* __restrict__ B,
              __hip_bfloat16* __restrict__ parts)
{
  constexpr int BK = 64, BKP = 72;     // +8 bf16 pad: read conflicts <=2-way (free)
  __shared__ short sA[2][128 * BKP];
  __shared__ short sB[2][128 * BKP];   // 73728 B total

  // bijective XCD swizzle, slice-major: XCD j gets 4 consecutive K-slices.
  const int n = gridDim.x;
  int lid = blockIdx.x;
  lid = (lid & 7) * (n >> 3) + (lid >> 3);
  const int y    = lid >> 5;           // 32 tiles per slice
  const int tile = lid & 31;
  const int tm = tile >> 3;            // 4 M-tiles
  const int tn = tile & 7;             // 8 N-tiles

  const int k0 = y * 1600;
  const int krem = KFLAT - k0;
  const int klen_eff = krem < 1600 ? krem : 1600;
  const int nt = klen_eff / BK;        // 25 (tail slice: 9)

  const int tid  = threadIdx.x;
  const int lane = tid & 63;
  const int wid  = tid >> 6;
  const int wm = wid >> 1, wn = wid & 1;
  const int l16 = lane & 15, kq = lane >> 4;

  const float* Ab = A + (size_t)(tm * 128) * KFLAT;
  const float* Bb = B + (size_t)(tn * 128) * KFLAT;

  f32x4 acc[4][4];
  #pragma unroll
  for (int i = 0; i < 4; ++i)
    #pragma unroll
    for (int j = 0; j < 4; ++j)
      acc[i][j] = (f32x4){0.f, 0.f, 0.f, 0.f};

  // staging: 128x64 fp32 per matrix per step = 32 floats/thread = 4 chunks of 8.
  float4 ra[4][2], rb[4][2];

  auto loadAB = [&](int kk) {
    #pragma unroll
    for (int i = 0; i < 4; ++i) {
      int ch = tid + i * 256;
      int r = ch >> 3, cc = ch & 7;
      const float* pa = Ab + (size_t)r * KFLAT + kk + cc * 8;
      const float* pb = Bb + (size_t)r * KFLAT + kk + cc * 8;
      ra[i][0] = *(const float4*)pa;
      ra[i][1] = *(const float4*)(pa + 4);
      rb[i][0] = *(const float4*)pb;
      rb[i][1] = *(const float4*)(pb + 4);
    }
  };
  auto storeAB = [&](int b) {
    #pragma unroll
    for (int i = 0; i < 4; ++i) {
      int ch = tid + i * 256;
      int r = ch >> 3, cc = ch & 7;
      float4 u = ra[i][0], v = ra[i][1];
      short8 s;
      s[0]=f2bf(u.x); s[1]=f2bf(u.y); s[2]=f2bf(u.z); s[3]=f2bf(u.w);
      s[4]=f2bf(v.x); s[5]=f2bf(v.y); s[6]=f2bf(v.z); s[7]=f2bf(v.w);
      *(short8*)&sA[b][r * BKP + cc * 8] = s;
      u = rb[i][0]; v = rb[i][1];
      s[0]=f2bf(u.x); s[1]=f2bf(u.y); s[2]=f2bf(u.z); s[3]=f2bf(u.w);
      s[4]=f2bf(v.x); s[5]=f2bf(v.y); s[6]=f2bf(v.z); s[7]=f2bf(v.w);
      *(short8*)&sB[b][r * BKP + cc * 8] = s;
    }
  };
  auto compute = [&](int b) {
    #pragma unroll
    for (int ks = 0; ks < 2; ++ks) {
      short8 af[4], bf[4];
      #pragma unroll
      for (int i = 0; i < 4; ++i)
        af[i] = *(short8*)&sA[b][(wm * 64 + i * 16 + l16) * BKP + ks * 32 + kq * 8];
      #pragma unroll
      for (int j = 0; j < 4; ++j)
        bf[j] = *(short8*)&sB[b][(wn * 64 + j * 16 + l16) * BKP + ks * 32 + kq * 8];
      #pragma unroll
      for (int i = 0; i < 4; ++i)
        #pragma unroll
        for (int j = 0; j < 4; ++j)
          acc[i][j] = __builtin_amdgcn_mfma_f32_16x16x32_bf16(af[i], bf[j], acc[i][j], 0, 0, 0);
    }
  };

  // prologue: tile0 -> buf0; issue loads for tile1.
  loadAB(k0);
  storeAB(0);
  if (nt > 1) loadAB(k0 + BK);
  __syncthreads();

  int cur = 0;
  for (int t = 0; t < nt; ++t) {
    if (t + 1 < nt) {
      storeAB(cur ^ 1);                       // regs for t+1 (issued iter t-1)
      if (t + 2 < nt) loadAB(k0 + (t + 2) * BK);  // 2-deep prefetch
    }
    compute(cur);                             // overlaps other waves' ds_write
    __syncthreads();                          // ONE barrier per K-step
    cur ^= 1;
  }

  __hip_bfloat16* P = parts + (size_t)y * (N_PROP * DHID);
  const int crow0 = tm * 128 + wm * 64;
  const int ccol0 = tn * 128 + wn * 64;
  #pragma unroll
  for (int i = 0; i < 4; ++i)
    #pragma unroll
    for (int j = 0; j < 4; ++j)
      #pragma unroll
      for (int e = 0; e < 4; ++e) {
        int r = crow0 + i * 16 + kq * 4 + e;
        int c = ccol0 + j * 16 + l16;
        P[(size_t)r * DHID + c] = __float2bfloat16(acc[i][j][e]);
      }
}

// ---------------- generic NT GEMM (small ops) — unchanged ------------------
template<int BM, int BN, int BK, int MINW>
__global__ __launch_bounds__(256, MINW)
void gemm_nt(const float* __restrict__ A, int lda,
             const float* __restrict__ B1, const float* __restrict__ B2, int ldb,
             float* __restrict__ C, __hip_bfloat16* __restrict__ Cb, int ldc,
             int tiles_per_slice, int tiles_n,
             int klen, int ktot,
             size_t c_split_stride, size_t c_z_stride,
             const float* __restrict__ bias1, const float* __restrict__ bias2,
             const float* __restrict__ res1, const float* __restrict__ res2,
             float* __restrict__ Ct, int ldct,
             int do_relu)
{
  constexpr int BKP = BK + 8;
  constexpr int WM = BM / 2, WN = BN / 2;
  constexpr int FM = WM / 16, FN = WN / 16;
  constexpr int NCH = BK / 8;
  constexpr int CHA = (BM * BK) / (8 * 256);
  constexpr int CHB = (BN * BK) / (8 * 256);

  __shared__ short As[BM * BKP];
  __shared__ short Bs[BN * BKP];

  const int n = gridDim.x;
  int lid = blockIdx.x;
  lid = (lid & 7) * (n >> 3) + (lid >> 3);

  const int y    = lid / tiles_per_slice;
  const int tile = lid % tiles_per_slice;
  const int tm = tile / tiles_n;
  const int tn = tile % tiles_n;

  const int k0 = y * klen;
  const int krem = ktot - k0;
  const int klen_eff = krem < klen ? krem : klen;
  const int nt = klen_eff / BK;

  const size_t coff = (size_t)y * c_split_stride + (size_t)blockIdx.z * c_z_stride;
  if (C)  C  += coff;
  if (Cb) Cb += coff;
  const float* B    = blockIdx.z ? B2 : B1;
  const float* bias = blockIdx.z ? bias2 : bias1;

  const int tid  = threadIdx.x;
  const int lane = tid & 63;
  const int wid  = tid >> 6;
  const int wm = wid >> 1, wn = wid & 1;
  const int l16 = lane & 15, kq = lane >> 4;

  const float* Abase = A + (size_t)(tm * BM) * lda;
  const float* Bbase = B + (size_t)(tn * BN) * ldb;

  f32x4 acc[FM][FN];
  #pragma unroll
  for (int i = 0; i < FM; ++i)
    #pragma unroll
    for (int j = 0; j < FN; ++j)
      acc[i][j] = (f32x4){0.f, 0.f, 0.f, 0.f};

  float4 ra[CHA][2], rb[CHB][2];

  auto loadA = [&](int kk) {
    #pragma unroll
    for (int i = 0; i < CHA; ++i) {
      int ch = tid + i * 256;
      int r = ch / NCH, cc = ch % NCH;
      const float* p = Abase + (size_t)r * lda + kk + cc * 8;
      ra[i][0] = *(const float4*)p;
      ra[i][1] = *(const float4*)(p + 4);
    }
  };
  auto loadB = [&](int kk) {
    #pragma unroll
    for (int i = 0; i < CHB; ++i) {
      int ch = tid + i * 256;
      int r = ch / NCH, cc = ch % NCH;
      const float* p = Bbase + (size_t)r * ldb + kk + cc * 8;
      rb[i][0] = *(const float4*)p;
      rb[i][1] = *(const float4*)(p + 4);
    }
  };
  auto storeAB = [&]() {
    #pragma unroll
    for (int i = 0; i < CHA; ++i) {
      int ch = tid + i * 256;
      int r = ch / NCH, cc = ch % NCH;
      float4 u = ra[i][0], v = ra[i][1];
      short8 s;
      s[0]=f2bf(u.x); s[1]=f2bf(u.y); s[2]=f2bf(u.z); s[3]=f2bf(u.w);
      s[4]=f2bf(v.x); s[5]=f2bf(v.y); s[6]=f2bf(v.z); s[7]=f2bf(v.w);
      *(short8*)&As[r * BKP + cc * 8] = s;
    }
    #pragma unroll
    for (int i = 0; i < CHB; ++i) {
      int ch = tid + i * 256;
      int r = ch / NCH, cc = ch % NCH;
      float4 u = rb[i][0], v = rb[i][1];
      short8 s;
      s[0]=f2bf(u.x); s[1]=f2bf(u.y); s[2]=f2bf(u.z); s[3]=f2bf(u.w);
      s[4]=f2bf(v.x); s[5]=f2bf(v.y); s[6]=f2bf(v.z); s[7]=f2bf(v.w);
      *(short8*)&Bs[r * BKP + cc * 8] = s;
    }
  };

  loadA(k0); loadB(k0);
  storeAB();
  __syncthreads();

  for (int t = 0; t < nt; ++t) {
    if (t + 1 < nt) { loadA(k0 + (t + 1) * BK); loadB(k0 + (t + 1) * BK); }

    #pragma unroll
    for (int ks = 0; ks < BK / 32; ++ks) {
      short8 af[FM], bf[FN];
      #pragma unroll
      for (int i = 0; i < FM; ++i)
        af[i] = *(short8*)&As[(wm * WM + i * 16 + l16) * BKP + ks * 32 + kq * 8];
      #pragma unroll
      for (int j = 0; j < FN; ++j)
        bf[j] = *(short8*)&Bs[(wn * WN + j * 16 + l16) * BKP + ks * 32 + kq * 8];
      #pragma unroll
      for (int i = 0; i < FM; ++i)
        #pragma unroll
        for (int j = 0; j < FN; ++j)
          acc[i][j] = __builtin_amdgcn_mfma_f32_16x16x32_bf16(af[i], bf[j], acc[i][j], 0, 0, 0);
    }

    __syncthreads();
    if (t + 1 < nt) storeAB();
    __syncthreads();
  }

  const int crow0 = tm * BM + wm * WM;
  const int ccol0 = tn * BN + wn * WN;
  #pragma unroll
  for (int i = 0; i < FM; ++i)
    #pragma unroll
    for (int j = 0; j < FN; ++j)
      #pragma unroll
      for (int e = 0; e < 4; ++e) {
        int r = crow0 + i * 16 + kq * 4 + e;
        int c = ccol0 + j * 16 + l16;
        float v = acc[i][j][e];
        if (bias) v += bias[c];
        if (res1) v += res1[(size_t)r * ldc + c];
        if (res2) v += res2[(size_t)r * ldc + c];
        if (do_relu) v = fmaxf(v, 0.f);
        if (Cb) Cb[(size_t)r * ldc + c] = __float2bfloat16(v);
        else    C [(size_t)r * ldc + c] = v;
        if (Ct) Ct[(size_t)c * ldct + r] = v;
      }
}

__global__ __launch_bounds__(256)
void reduce_bias(const __hip_bfloat16* __restrict__ parts, int sk, size_t stride,
                 const float* __restrict__ bias, float* __restrict__ out)
{
  int idx4 = blockIdx.x * 256 + threadIdx.x;
  int c4 = idx4 & (DHID / 4 - 1);
  float4 b = *(const float4*)(bias + (size_t)c4 * 4);
  float s0 = b.x, s1 = b.y, s2 = b.z, s3 = b.w;
  for (int i = 0; i < sk; ++i) {
    const __hip_bfloat16* p = parts + (size_t)i * stride + (size_t)idx4 * 4;
    ushort4 u = *(const ushort4*)p;
    s0 += bf2f(u.x); s1 += bf2f(u.y); s2 += bf2f(u.z); s3 += bf2f(u.w);
  }
  float4 o = {s0, s1, s2, s3};
  *(float4*)(out + (size_t)idx4 * 4) = o;
}

__global__ __launch_bounds__(256)
void transpose_k(const float* __restrict__ in, float* __restrict__ out, int R, int Cc)
{
  __shared__ float t[32][33];
  int bx = blockIdx.x * 32;
  int by = blockIdx.y * 32;
  int tx = threadIdx.x & 31, ty = threadIdx.x >> 5;
  #pragma unroll
  for (int i = 0; i < 4; ++i)
    t[ty + i * 8][tx] = in[(size_t)(by + ty + i * 8) * Cc + bx + tx];
  __syncthreads();
  #pragma unroll
  for (int i = 0; i < 4; ++i)
    out[(size_t)(bx + ty + i * 8) * R + by + tx] = t[tx][ty + i * 8];
}

__global__ __launch_bounds__(256)
void softmax_rows(float* __restrict__ x, float scale)
{
  int row = blockIdx.x;
  float* p = x + (size_t)row * N_PROP;
  int tid = threadIdx.x;
  float a = p[tid] * scale;
  float b = p[tid + 256] * scale;
  float m = fmaxf(a, b);
  #pragma unroll
  for (int o = 32; o > 0; o >>= 1) m = fmaxf(m, __shfl_xor(m, o));
  __shared__ float sm[4], ss[4];
  int w = tid >> 6;
  if ((tid & 63) == 0) sm[w] = m;
  __syncthreads();
  m = fmaxf(fmaxf(sm[0], sm[1]), fmaxf(sm[2], sm[3]));
  float ea = __expf(a - m), eb = __expf(b - m);
  float s = ea + eb;
  #pragma unroll
  for (int o = 32; o > 0; o >>= 1) s += __shfl_xor(s, o);
  if ((tid & 63) == 0) ss[w] = s;
  __syncthreads();
  s = ss[0] + ss[1] + ss[2] + ss[3];
  float inv = 1.f / s;
  p[tid] = ea * inv;
  p[tid + 256] = eb * inv;
}

extern "C" void kernel_launch(void* const* d_in, const int* in_sizes, int n_in,
                              void* d_out, int out_size, void* d_ws, size_t ws_size,
                              hipStream_t stream)
{
  (void)in_sizes; (void)n_in; (void)out_size; (void)ws_size;
  const float* x      = (const float*)d_in[0];
  const float* fc1_w  = (const float*)d_in[1];
  const float* fc1_b  = (const float*)d_in[2];
  const float* fc2_w  = (const float*)d_in[3];
  const float* fc2_b  = (const float*)d_in[4];
  const float* a1w1   = (const float*)d_in[5];
  const float* a1b1   = (const float*)d_in[6];
  const float* a1w2   = (const float*)d_in[7];
  const float* a1b2   = (const float*)d_in[8];
  const float* a1cw   = (const float*)d_in[9];
  const float* a1cb   = (const float*)d_in[10];
  const float* a2w1   = (const float*)d_in[11];
  const float* a2b1   = (const float*)d_in[12];
  const float* a2w2   = (const float*)d_in[13];
  const float* a2b2   = (const float*)d_in[14];
  const float* a2cw   = (const float*)d_in[15];
  const float* a2cb   = (const float*)d_in[16];
  float* out = (float*)d_out;

  char* ws = (char*)d_ws;
  const size_t SZ = (size_t)N_PROP * DHID * 4;      // 2 MB
  float* out0   = (float*)(ws + 0 * SZ);
  float* h0     = (float*)(ws + 1 * SZ);
  float* h1     = (float*)(ws + 2 * SZ);
  float* T      = (float*)(ws + 3 * SZ);
  float* q      = (float*)(ws + 4 * SZ);
  float* k      = (float*)(ws + 5 * SZ);            // adjacent to q (dual-z)
  float* att    = (float*)(ws + 6 * SZ);
  float* logits = (float*)(ws + 7 * SZ);
  __hip_bfloat16* parts =
      (__hip_bfloat16*)(ws + 7 * SZ + (size_t)N_PROP * N_PROP * 4);  // 32 x 1 MB

  const size_t ND = (size_t)N_PROP * DHID;
  const int SK = 32;
  dim3 blk(256);

  // ---- fc1 ----
  gemm_fc1<<<dim3(32 * SK), blk, 0, stream>>>(x, fc1_w, parts);
  reduce_bias<<<(N_PROP * DHID) / 1024, blk, 0, stream>>>(parts, SK, ND, fc1_b, out0);

  // ---- attention 1 on out0 ----
  transpose_k<<<dim3(DHID / 32, N_PROP / 32), blk, 0, stream>>>(out0, T, N_PROP, DHID);
  gemm_nt<32, 64, 128, 2><<<dim3(256, 1, 2), blk, 0, stream>>>(
      out0, DHID, a1w1, a1w2, DHID,
      q, nullptr, DHID,
      256, 16, DHID, DHID,
      0, ND,
      a1b1, a1b2, nullptr, nullptr, nullptr, 0, 0);
  gemm_nt<32, 32, 128, 2><<<dim3(256), blk, 0, stream>>>(
      q, DHID, k, nullptr, DHID,
      logits, nullptr, N_PROP,
      256, 16, DHID, DHID,
      0, 0,
      nullptr, nullptr, nullptr, nullptr, nullptr, 0, 0);
  softmax_rows<<<N_PROP, blk, 0, stream>>>(logits, SM_SCALE);
  gemm_nt<32, 64, 128, 2><<<dim3(256), blk, 0, stream>>>(
      logits, N_PROP, T, nullptr, N_PROP,
      att, nullptr, DHID,
      256, 16, N_PROP, N_PROP,
      0, 0,
      nullptr, nullptr, nullptr, nullptr, nullptr, 0, 0);
  gemm_nt<32, 64, 128, 2><<<dim3(256), blk, 0, stream>>>(
      att, DHID, a1cw, nullptr, DHID,
      h0, nullptr, DHID,
      256, 16, DHID, DHID,
      0, 0,
      a1cb, nullptr, out0, nullptr, nullptr, 0, 1);
  gemm_nt<32, 64, 128, 2><<<dim3(256), blk, 0, stream>>>(
      h0, DHID, fc2_w, nullptr, DHID,
      h1, nullptr, DHID,
      256, 16, DHID, DHID,
      0, 0,
      fc2_b, nullptr, nullptr, nullptr, T, N_PROP, 0);

  // ---- attention 2 on h1 ----
  gemm_nt<32, 64, 128, 2><<<dim3(256, 1, 2), blk, 0, stream>>>(
      h1, DHID, a2w1, a2w2, DHID,
      q, nullptr, DHID,
      256, 16, DHID, DHID,
      0, ND,
      a2b1, a2b2, nullptr, nullptr, nullptr, 0, 0);
  gemm_nt<32, 32, 128, 2><<<dim3(256), blk, 0, stream>>>(
      q, DHID, k, nullptr, DHID,
      logits, nullptr, N_PROP,
      256, 16, DHID, DHID,
      0, 0,
      nullptr, nullptr, nullptr, nullptr, nullptr, 0, 0);
  softmax_rows<<<N_PROP, blk, 0, stream>>>(logits, SM_SCALE);
  gemm_nt<32, 64, 128, 2><<<dim3(256), blk, 0, stream>>>(
      logits, N_PROP, T, nullptr, N_PROP,
      att, nullptr, DHID,
      256, 16, N_PROP, N_PROP,
      0, 0,
      nullptr, nullptr, nullptr, nullptr, nullptr, 0, 0);
  gemm_nt<32, 64, 128, 2><<<dim3(256), blk, 0, stream>>>(
      att, DHID, a2cw, nullptr, DHID,
      out, nullptr, DHID,
      256, 16, DHID, DHID,
      0, 0,
      a2cb, nullptr, h1, out0, nullptr, 0, 1);
}

// Round 7
// 217.977 us; speedup vs baseline: 1.2843x; 1.1767x over previous
//
#include <hip/hip_runtime.h>
#include <hip/hip_bf16.h>

typedef __attribute__((ext_vector_type(8))) short short8;
typedef __attribute__((ext_vector_type(4))) float f32x4;

#define N_PROP 512
#define DHID   1024
#define KFLAT  50176
#define SM_SCALE 0.03125f  /* 1/sqrt(1024) */

__device__ inline short f2bf(float x) {
  __hip_bfloat16 b = __float2bfloat16(x);
  return __builtin_bit_cast(short, b);
}
__device__ inline float bf2f(unsigned short u) {
  unsigned int x = (unsigned int)u << 16;
  return __builtin_bit_cast(float, x);
}

// ---------------- fc1: 256x256 tile, 16 waves, BK=32, bf16 dbuf LDS ---------
// parts[y] = A(256-rows) @ B(256-rows)^T over klen=1568 (=49*32, uniform).
// Tile FLOP/staged-byte = 64 (2x the 128^2 tile): per thread per K-step only
// 4 float4 loads + 16 cvt + 2 ds_write + 8 ds_read vs 16 MFMA.
// acc 64 VGPR + stage 16 -> ~110 live: fits 4 waves/SIMD (launch_bounds 1024,4).
// (round-3 lesson: if WRITE_SIZE explodes, the cap spilled — revert to MINW 2.)
__global__ __launch_bounds__(1024, 4)
void gemm_fc1(const float* __restrict__ A, const float* __restrict__ B,
              __hip_bfloat16* __restrict__ parts)
{
  constexpr int BK = 32, BKP = 40;     // bf16 row stride 80B -> 2-way read conflicts (free)
  constexpr int KLEN = 1568, NT = KLEN / BK;   // 49
  __shared__ short sA[2][256 * BKP];
  __shared__ short sB[2][256 * BKP];   // 81920 B total

  // bijective XCD swizzle, slice-major: XCD j gets 4 consecutive K-slices.
  const int n = gridDim.x;
  int lid = blockIdx.x;
  lid = (lid & 7) * (n >> 3) + (lid >> 3);
  const int y    = lid >> 3;           // 32 slices
  const int tile = lid & 7;
  const int tm = tile >> 2;            // 2 M-tiles
  const int tn = tile & 3;             // 4 N-tiles

  const int k0 = y * KLEN;

  const int tid  = threadIdx.x;
  const int lane = tid & 63;
  const int wid  = tid >> 6;           // 16 waves
  const int wr = wid >> 2, wc = wid & 3;
  const int l16 = lane & 15, kq = lane >> 4;

  const float* Ab = A + (size_t)(tm * 256) * KFLAT;
  const float* Bb = B + (size_t)(tn * 256) * KFLAT;

  // staging: each matrix tile is 256x32 fp32 = 8192 floats -> 8 floats/thread.
  const int srow = tid >> 2;           // 256 rows
  const int scol = (tid & 3) * 8;      // 4 chunks of 8 floats

  f32x4 acc[4][4];
  #pragma unroll
  for (int i = 0; i < 4; ++i)
    #pragma unroll
    for (int j = 0; j < 4; ++j)
      acc[i][j] = (f32x4){0.f, 0.f, 0.f, 0.f};

  float4 ra0, ra1, rb0, rb1;

  auto loadAB = [&](int kk) {
    const float* pa = Ab + (size_t)srow * KFLAT + kk + scol;
    const float* pb = Bb + (size_t)srow * KFLAT + kk + scol;
    ra0 = *(const float4*)pa; ra1 = *(const float4*)(pa + 4);
    rb0 = *(const float4*)pb; rb1 = *(const float4*)(pb + 4);
  };
  auto storeAB = [&](int b) {
    short8 s;
    s[0]=f2bf(ra0.x); s[1]=f2bf(ra0.y); s[2]=f2bf(ra0.z); s[3]=f2bf(ra0.w);
    s[4]=f2bf(ra1.x); s[5]=f2bf(ra1.y); s[6]=f2bf(ra1.z); s[7]=f2bf(ra1.w);
    *(short8*)&sA[b][srow * BKP + scol] = s;
    s[0]=f2bf(rb0.x); s[1]=f2bf(rb0.y); s[2]=f2bf(rb0.z); s[3]=f2bf(rb0.w);
    s[4]=f2bf(rb1.x); s[5]=f2bf(rb1.y); s[6]=f2bf(rb1.z); s[7]=f2bf(rb1.w);
    *(short8*)&sB[b][srow * BKP + scol] = s;
  };
  auto compute = [&](int b) {
    short8 af[4], bf[4];
    #pragma unroll
    for (int i = 0; i < 4; ++i)
      af[i] = *(short8*)&sA[b][(wr * 64 + i * 16 + l16) * BKP + kq * 8];
    #pragma unroll
    for (int j = 0; j < 4; ++j)
      bf[j] = *(short8*)&sB[b][(wc * 64 + j * 16 + l16) * BKP + kq * 8];
    #pragma unroll
    for (int i = 0; i < 4; ++i)
      #pragma unroll
      for (int j = 0; j < 4; ++j)
        acc[i][j] = __builtin_amdgcn_mfma_f32_16x16x32_bf16(af[i], bf[j], acc[i][j], 0, 0, 0);
  };

  // prologue: tile0 -> buf0; issue loads for tile1.
  loadAB(k0);
  storeAB(0);
  loadAB(k0 + BK);
  __syncthreads();

  int cur = 0;
  for (int t = 0; t < NT; ++t) {
    if (t + 1 < NT) {
      storeAB(cur ^ 1);                           // regs for t+1
      if (t + 2 < NT) loadAB(k0 + (t + 2) * BK);  // prefetch t+2
    }
    compute(cur);                                 // overlaps other waves' ds_write
    __syncthreads();                              // ONE barrier per K-step
    cur ^= 1;
  }

  __hip_bfloat16* P = parts + (size_t)y * (N_PROP * DHID);
  const int crow0 = tm * 256 + wr * 64;
  const int ccol0 = tn * 256 + wc * 64;
  #pragma unroll
  for (int i = 0; i < 4; ++i)
    #pragma unroll
    for (int j = 0; j < 4; ++j)
      #pragma unroll
      for (int e = 0; e < 4; ++e) {
        int r = crow0 + i * 16 + kq * 4 + e;
        int c = ccol0 + j * 16 + l16;
        P[(size_t)r * DHID + c] = __float2bfloat16(acc[i][j][e]);
      }
}

// ---------------- generic NT GEMM (small ops) — unchanged ------------------
template<int BM, int BN, int BK, int MINW>
__global__ __launch_bounds__(256, MINW)
void gemm_nt(const float* __restrict__ A, int lda,
             const float* __restrict__ B1, const float* __restrict__ B2, int ldb,
             float* __restrict__ C, __hip_bfloat16* __restrict__ Cb, int ldc,
             int tiles_per_slice, int tiles_n,
             int klen, int ktot,
             size_t c_split_stride, size_t c_z_stride,
             const float* __restrict__ bias1, const float* __restrict__ bias2,
             const float* __restrict__ res1, const float* __restrict__ res2,
             float* __restrict__ Ct, int ldct,
             int do_relu)
{
  constexpr int BKP = BK + 8;
  constexpr int WM = BM / 2, WN = BN / 2;
  constexpr int FM = WM / 16, FN = WN / 16;
  constexpr int NCH = BK / 8;
  constexpr int CHA = (BM * BK) / (8 * 256);
  constexpr int CHB = (BN * BK) / (8 * 256);

  __shared__ short As[BM * BKP];
  __shared__ short Bs[BN * BKP];

  const int n = gridDim.x;
  int lid = blockIdx.x;
  lid = (lid & 7) * (n >> 3) + (lid >> 3);

  const int y    = lid / tiles_per_slice;
  const int tile = lid % tiles_per_slice;
  const int tm = tile / tiles_n;
  const int tn = tile % tiles_n;

  const int k0 = y * klen;
  const int krem = ktot - k0;
  const int klen_eff = krem < klen ? krem : klen;
  const int nt = klen_eff / BK;

  const size_t coff = (size_t)y * c_split_stride + (size_t)blockIdx.z * c_z_stride;
  if (C)  C  += coff;
  if (Cb) Cb += coff;
  const float* B    = blockIdx.z ? B2 : B1;
  const float* bias = blockIdx.z ? bias2 : bias1;

  const int tid  = threadIdx.x;
  const int lane = tid & 63;
  const int wid  = tid >> 6;
  const int wm = wid >> 1, wn = wid & 1;
  const int l16 = lane & 15, kq = lane >> 4;

  const float* Abase = A + (size_t)(tm * BM) * lda;
  const float* Bbase = B + (size_t)(tn * BN) * ldb;

  f32x4 acc[FM][FN];
  #pragma unroll
  for (int i = 0; i < FM; ++i)
    #pragma unroll
    for (int j = 0; j < FN; ++j)
      acc[i][j] = (f32x4){0.f, 0.f, 0.f, 0.f};

  float4 ra[CHA][2], rb[CHB][2];

  auto loadA = [&](int kk) {
    #pragma unroll
    for (int i = 0; i < CHA; ++i) {
      int ch = tid + i * 256;
      int r = ch / NCH, cc = ch % NCH;
      const float* p = Abase + (size_t)r * lda + kk + cc * 8;
      ra[i][0] = *(const float4*)p;
      ra[i][1] = *(const float4*)(p + 4);
    }
  };
  auto loadB = [&](int kk) {
    #pragma unroll
    for (int i = 0; i < CHB; ++i) {
      int ch = tid + i * 256;
      int r = ch / NCH, cc = ch % NCH;
      const float* p = Bbase + (size_t)r * ldb + kk + cc * 8;
      rb[i][0] = *(const float4*)p;
      rb[i][1] = *(const float4*)(p + 4);
    }
  };
  auto storeAB = [&]() {
    #pragma unroll
    for (int i = 0; i < CHA; ++i) {
      int ch = tid + i * 256;
      int r = ch / NCH, cc = ch % NCH;
      float4 u = ra[i][0], v = ra[i][1];
      short8 s;
      s[0]=f2bf(u.x); s[1]=f2bf(u.y); s[2]=f2bf(u.z); s[3]=f2bf(u.w);
      s[4]=f2bf(v.x); s[5]=f2bf(v.y); s[6]=f2bf(v.z); s[7]=f2bf(v.w);
      *(short8*)&As[r * BKP + cc * 8] = s;
    }
    #pragma unroll
    for (int i = 0; i < CHB; ++i) {
      int ch = tid + i * 256;
      int r = ch / NCH, cc = ch % NCH;
      float4 u = rb[i][0], v = rb[i][1];
      short8 s;
      s[0]=f2bf(u.x); s[1]=f2bf(u.y); s[2]=f2bf(u.z); s[3]=f2bf(u.w);
      s[4]=f2bf(v.x); s[5]=f2bf(v.y); s[6]=f2bf(v.z); s[7]=f2bf(v.w);
      *(short8*)&Bs[r * BKP + cc * 8] = s;
    }
  };

  loadA(k0); loadB(k0);
  storeAB();
  __syncthreads();

  for (int t = 0; t < nt; ++t) {
    if (t + 1 < nt) { loadA(k0 + (t + 1) * BK); loadB(k0 + (t + 1) * BK); }

    #pragma unroll
    for (int ks = 0; ks < BK / 32; ++ks) {
      short8 af[FM], bf[FN];
      #pragma unroll
      for (int i = 0; i < FM; ++i)
        af[i] = *(short8*)&As[(wm * WM + i * 16 + l16) * BKP + ks * 32 + kq * 8];
      #pragma unroll
      for (int j = 0; j < FN; ++j)
        bf[j] = *(short8*)&Bs[(wn * WN + j * 16 + l16) * BKP + ks * 32 + kq * 8];
      #pragma unroll
      for (int i = 0; i < FM; ++i)
        #pragma unroll
        for (int j = 0; j < FN; ++j)
          acc[i][j] = __builtin_amdgcn_mfma_f32_16x16x32_bf16(af[i], bf[j], acc[i][j], 0, 0, 0);
    }

    __syncthreads();
    if (t + 1 < nt) storeAB();
    __syncthreads();
  }

  const int crow0 = tm * BM + wm * WM;
  const int ccol0 = tn * BN + wn * WN;
  #pragma unroll
  for (int i = 0; i < FM; ++i)
    #pragma unroll
    for (int j = 0; j < FN; ++j)
      #pragma unroll
      for (int e = 0; e < 4; ++e) {
        int r = crow0 + i * 16 + kq * 4 + e;
        int c = ccol0 + j * 16 + l16;
        float v = acc[i][j][e];
        if (bias) v += bias[c];
        if (res1) v += res1[(size_t)r * ldc + c];
        if (res2) v += res2[(size_t)r * ldc + c];
        if (do_relu) v = fmaxf(v, 0.f);
        if (Cb) Cb[(size_t)r * ldc + c] = __float2bfloat16(v);
        else    C [(size_t)r * ldc + c] = v;
        if (Ct) Ct[(size_t)c * ldct + r] = v;
      }
}

__global__ __launch_bounds__(256)
void reduce_bias(const __hip_bfloat16* __restrict__ parts, int sk, size_t stride,
                 const float* __restrict__ bias, float* __restrict__ out)
{
  int idx4 = blockIdx.x * 256 + threadIdx.x;
  int c4 = idx4 & (DHID / 4 - 1);
  float4 b = *(const float4*)(bias + (size_t)c4 * 4);
  float s0 = b.x, s1 = b.y, s2 = b.z, s3 = b.w;
  for (int i = 0; i < sk; ++i) {
    const __hip_bfloat16* p = parts + (size_t)i * stride + (size_t)idx4 * 4;
    ushort4 u = *(const ushort4*)p;
    s0 += bf2f(u.x); s1 += bf2f(u.y); s2 += bf2f(u.z); s3 += bf2f(u.w);
  }
  float4 o = {s0, s1, s2, s3};
  *(float4*)(out + (size_t)idx4 * 4) = o;
}

__global__ __launch_bounds__(256)
void transpose_k(const float* __restrict__ in, float* __restrict__ out, int R, int Cc)
{
  __shared__ float t[32][33];
  int bx = blockIdx.x * 32;
  int by = blockIdx.y * 32;
  int tx = threadIdx.x & 31, ty = threadIdx.x >> 5;
  #pragma unroll
  for (int i = 0; i < 4; ++i)
    t[ty + i * 8][tx] = in[(size_t)(by + ty + i * 8) * Cc + bx + tx];
  __syncthreads();
  #pragma unroll
  for (int i = 0; i < 4; ++i)
    out[(size_t)(bx + ty + i * 8) * R + by + tx] = t[tx][ty + i * 8];
}

__global__ __launch_bounds__(256)
void softmax_rows(float* __restrict__ x, float scale)
{
  int row = blockIdx.x;
  float* p = x + (size_t)row * N_PROP;
  int tid = threadIdx.x;
  float a = p[tid] * scale;
  float b = p[tid + 256] * scale;
  float m = fmaxf(a, b);
  #pragma unroll
  for (int o = 32; o > 0; o >>= 1) m = fmaxf(m, __shfl_xor(m, o));
  __shared__ float sm[4], ss[4];
  int w = tid >> 6;
  if ((tid & 63) == 0) sm[w] = m;
  __syncthreads();
  m = fmaxf(fmaxf(sm[0], sm[1]), fmaxf(sm[2], sm[3]));
  float ea = __expf(a - m), eb = __expf(b - m);
  float s = ea + eb;
  #pragma unroll
  for (int o = 32; o > 0; o >>= 1) s += __shfl_xor(s, o);
  if ((tid & 63) == 0) ss[w] = s;
  __syncthreads();
  s = ss[0] + ss[1] + ss[2] + ss[3];
  float inv = 1.f / s;
  p[tid] = ea * inv;
  p[tid + 256] = eb * inv;
}

extern "C" void kernel_launch(void* const* d_in, const int* in_sizes, int n_in,
                              void* d_out, int out_size, void* d_ws, size_t ws_size,
                              hipStream_t stream)
{
  (void)in_sizes; (void)n_in; (void)out_size; (void)ws_size;
  const float* x      = (const float*)d_in[0];
  const float* fc1_w  = (const float*)d_in[1];
  const float* fc1_b  = (const float*)d_in[2];
  const float* fc2_w  = (const float*)d_in[3];
  const float* fc2_b  = (const float*)d_in[4];
  const float* a1w1   = (const float*)d_in[5];
  const float* a1b1   = (const float*)d_in[6];
  const float* a1w2   = (const float*)d_in[7];
  const float* a1b2   = (const float*)d_in[8];
  const float* a1cw   = (const float*)d_in[9];
  const float* a1cb   = (const float*)d_in[10];
  const float* a2w1   = (const float*)d_in[11];
  const float* a2b1   = (const float*)d_in[12];
  const float* a2w2   = (const float*)d_in[13];
  const float* a2b2   = (const float*)d_in[14];
  const float* a2cw   = (const float*)d_in[15];
  const float* a2cb   = (const float*)d_in[16];
  float* out = (float*)d_out;

  char* ws = (char*)d_ws;
  const size_t SZ = (size_t)N_PROP * DHID * 4;      // 2 MB
  float* out0   = (float*)(ws + 0 * SZ);
  float* h0     = (float*)(ws + 1 * SZ);
  float* h1     = (float*)(ws + 2 * SZ);
  float* T      = (float*)(ws + 3 * SZ);
  float* q      = (float*)(ws + 4 * SZ);
  float* k      = (float*)(ws + 5 * SZ);            // adjacent to q (dual-z)
  float* att    = (float*)(ws + 6 * SZ);
  float* logits = (float*)(ws + 7 * SZ);
  __hip_bfloat16* parts =
      (__hip_bfloat16*)(ws + 7 * SZ + (size_t)N_PROP * N_PROP * 4);  // 32 x 1 MB

  const size_t ND = (size_t)N_PROP * DHID;
  const int SK = 32;
  dim3 blk(256);

  // ---- fc1: 256^2 tile, 1024 threads, SK=32 (klen 1568 = 49*32 uniform) ----
  gemm_fc1<<<dim3(8 * SK), dim3(1024), 0, stream>>>(x, fc1_w, parts);
  reduce_bias<<<(N_PROP * DHID) / 1024, blk, 0, stream>>>(parts, SK, ND, fc1_b, out0);

  // ---- attention 1 on out0 ----
  transpose_k<<<dim3(DHID / 32, N_PROP / 32), blk, 0, stream>>>(out0, T, N_PROP, DHID);
  gemm_nt<32, 64, 128, 2><<<dim3(256, 1, 2), blk, 0, stream>>>(
      out0, DHID, a1w1, a1w2, DHID,
      q, nullptr, DHID,
      256, 16, DHID, DHID,
      0, ND,
      a1b1, a1b2, nullptr, nullptr, nullptr, 0, 0);
  gemm_nt<32, 32, 128, 2><<<dim3(256), blk, 0, stream>>>(
      q, DHID, k, nullptr, DHID,
      logits, nullptr, N_PROP,
      256, 16, DHID, DHID,
      0, 0,
      nullptr, nullptr, nullptr, nullptr, nullptr, 0, 0);
  softmax_rows<<<N_PROP, blk, 0, stream>>>(logits, SM_SCALE);
  gemm_nt<32, 64, 128, 2><<<dim3(256), blk, 0, stream>>>(
      logits, N_PROP, T, nullptr, N_PROP,
      att, nullptr, DHID,
      256, 16, N_PROP, N_PROP,
      0, 0,
      nullptr, nullptr, nullptr, nullptr, nullptr, 0, 0);
  gemm_nt<32, 64, 128, 2><<<dim3(256), blk, 0, stream>>>(
      att, DHID, a1cw, nullptr, DHID,
      h0, nullptr, DHID,
      256, 16, DHID, DHID,
      0, 0,
      a1cb, nullptr, out0, nullptr, nullptr, 0, 1);
  gemm_nt<32, 64, 128, 2><<<dim3(256), blk, 0, stream>>>(
      h0, DHID, fc2_w, nullptr, DHID,
      h1, nullptr, DHID,
      256, 16, DHID, DHID,
      0, 0,
      fc2_b, nullptr, nullptr, nullptr, T, N_PROP, 0);

  // ---- attention 2 on h1 ----
  gemm_nt<32, 64, 128, 2><<<dim3(256, 1, 2), blk, 0, stream>>>(
      h1, DHID, a2w1, a2w2, DHID,
      q, nullptr, DHID,
      256, 16, DHID, DHID,
      0, ND,
      a2b1, a2b2, nullptr, nullptr, nullptr, 0, 0);
  gemm_nt<32, 32, 128, 2><<<dim3(256), blk, 0, stream>>>(
      q, DHID, k, nullptr, DHID,
      logits, nullptr, N_PROP,
      256, 16, DHID, DHID,
      0, 0,
      nullptr, nullptr, nullptr, nullptr, nullptr, 0, 0);
  softmax_rows<<<N_PROP, blk, 0, stream>>>(logits, SM_SCALE);
  gemm_nt<32, 64, 128, 2><<<dim3(256), blk, 0, stream>>>(
      logits, N_PROP, T, nullptr, N_PROP,
      att, nullptr, DHID,
      256, 16, N_PROP, N_PROP,
      0, 0,
      nullptr, nullptr, nullptr, nullptr, nullptr, 0, 0);
  gemm_nt<32, 64, 128, 2><<<dim3(256), blk, 0, stream>>>(
      att, DHID, a2cw, nullptr, DHID,
      out, nullptr, DHID,
      256, 16, DHID, DHID,
      0, 0,
      a2cb, nullptr, h1, out0, nullptr, 0, 1);
}